// Round 11
// baseline (82.627 us; speedup 1.0000x reference)
//
#include <hip/hip_runtime.h>

#define NNODE 8
#define FDIM 512
#define HDIM 256
#define ODIM 128
#define BATCH 8192
#define OC 4                 // columns per block
#define NQG (ODIM / OC)      // 32 column groups
#define NSH 2                // sample halves
#define SHS (BATCH / NSH)    // 4096
#define NCHK 32              // scan chunks
#define CEV (HDIM / NCHK)    // 8 events per chunk

__global__ __launch_bounds__(1024) void gnn_mono(
    const float* __restrict__ latent, const float* __restrict__ nf,
    const float* __restrict__ ea, const float* __restrict__ b1,
    const float* __restrict__ W1, const float* __restrict__ W2,
    const float* __restrict__ b2, float* __restrict__ out)
{
    const int tid = threadIdx.x;
    const int blk = blockIdx.x;
    // XCD-friendly column mapping: consecutive column groups land on one XCD
    const int qg   = (blk & 7) * 4 + ((blk >> 3) & 3);
    const int shh  = blk >> 5;            // sample half
    const int obase = qg * OC;

    __shared__ float tabA[NNODE * 257 * OC];    // 32.1 KiB  A plane (16B rows)
    __shared__ float tabB[NNODE * 257 * OC];    // 32.1 KiB  B plane
    __shared__ float tau_u[NNODE * HDIM];       // 8 KiB unsorted tau
    __shared__ float tau_srt[NNODE * HDIM];     // 8 KiB sorted tau
    __shared__ int   hs_s[NNODE * HDIM];        // 8 KiB rank -> h
    __shared__ float A_s[64], dinv_s[NNODE], m_s[NNODE];
    __shared__ float R1[4 * NNODE * HDIM + 4 * HDIM]; // 36 KiB: pp[4][8][256]+ss[4][256] -> pP/pK/bp/bk[8][256]
    __shared__ float R2[NNODE * FDIM];                // 16 KiB: v[8][512] -> cta/ctb/eta/etb[8][OC][NCHK]

    float* pp  = R1;                        // [g][j][h]
    float* ss  = R1 + 4 * NNODE * HDIM;     // [g][h]
    float* pP  = R1;                        // overlay after prep
    float* pK  = R1 + NNODE * HDIM;
    float* bpA = R1 + 2 * NNODE * HDIM;
    float* bkA = R1 + 3 * NNODE * HDIM;
    float* v_s = R2;                        // [j][f]
    float* cta = R2;                        // overlay in scan
    float* ctb = R2 + NNODE * OC * NCHK;
    float* eta = R2 + 2 * NNODE * OC * NCHK;
    float* etb = R2 + 3 * NNODE * OC * NCHK;

    // ---------------- A_hat (parallel) ----------------
    if (tid < 64) {
        int i = tid >> 3, qn = tid & 7;
        float a = (i == qn) ? 1.f : 0.f;
        if (i != qn) a += ea[qn * 7 + i - (i > qn ? 1 : 0)];   // edge src=qn, dst=i
        A_s[tid] = a;
    }
    __syncthreads();
    if (tid < NNODE) {
        float d = 0.f;
#pragma unroll
        for (int qq = 0; qq < NNODE; qq++) d += A_s[tid * 8 + qq];
        dinv_s[tid] = d > 0.f ? 1.0f / sqrtf(d) : 0.f;
    }
    __syncthreads();
    if (tid < 64) {
        int i = tid >> 3, qn = tid & 7;
        A_s[tid] = dinv_s[i] * A_s[tid] * dinv_s[qn];
    }
    __syncthreads();
    if (tid < NNODE) {
        float mm = 0.f;
#pragma unroll
        for (int i = 0; i < NNODE; i++) mm += A_s[i * 8 + tid];
        m_s[tid] = mm * 0.125f;
    }

    // ---------------- v[j][f] = (A_hat @ NF)[j][f] ----------------
    {
        int f = tid & (FDIM - 1);
        int jh = tid >> 9;     // 0/1 -> j in [jh*4, jh*4+4)
        float nfv[NNODE];
#pragma unroll
        for (int n = 0; n < NNODE; n++) nfv[n] = nf[n * FDIM + f];
#pragma unroll
        for (int u = 0; u < 4; u++) {
            int j = jh * 4 + u;
            float vv = 0.f;
#pragma unroll
            for (int n = 0; n < NNODE; n++) vv = fmaf(A_s[j * 8 + n], nfv[n], vv);
            v_s[j * FDIM + f] = vv;
        }
    }
    __syncthreads();

    // ---------------- P dots: pp[g][j][h], ss[g][h] ----------------
    {
        const int h = tid & 255;
        const int g = tid >> 8;
        const float* Wp = W1 + (size_t)(g * 128) * HDIM + h;
        float acc[NNODE];
#pragma unroll
        for (int j = 0; j < NNODE; j++) acc[j] = 0.f;
        float s1 = 0.f;
        for (int f4 = 0; f4 < 32; f4++) {
            float4 vv[NNODE];
#pragma unroll
            for (int j = 0; j < NNODE; j++)
                vv[j] = *(const float4*)&v_s[j * FDIM + g * 128 + f4 * 4];
#pragma unroll
            for (int k = 0; k < 4; k++) {
                float wv = Wp[(size_t)(f4 * 4 + k) * HDIM];
                s1 += wv;
#pragma unroll
                for (int j = 0; j < NNODE; j++)
                    acc[j] = fmaf(((const float*)&vv[j])[k], wv, acc[j]);
            }
        }
#pragma unroll
        for (int j = 0; j < NNODE; j++) pp[g * (NNODE * HDIM) + j * HDIM + h] = acc[j];
        ss[g * HDIM + h] = s1;
    }
    __syncthreads();

    // ---------------- prep: P, kappa, tau (2 (j,h) pairs/thread) ----------------
    float Pr[2], Kr[2], Tr[2];
    int Jr[2], Hr[2];
#pragma unroll
    for (int u = 0; u < 2; u++) {
        int p = tid + u * 1024;
        int j = p >> 8, h = p & 255;
        float P = b1[h];
#pragma unroll
        for (int g = 0; g < 4; g++) P += pp[g * (NNODE * HDIM) + j * HDIM + h];
        float s1 = ss[h] + ss[HDIM + h] + ss[2 * HDIM + h] + ss[3 * HDIM + h];
        float kap = 0.1f * s1;
        float tau = (kap != 0.f) ? (-P / kap) : __builtin_inff();
        tau_u[j * HDIM + h] = tau;
        Pr[u] = P; Kr[u] = kap; Tr[u] = tau; Jr[u] = j; Hr[u] = h;
    }
    __syncthreads();   // tau_u complete; pp/ss reads done -> R1 reusable

    // rank sort + event coeffs (by h index)
#pragma unroll
    for (int u = 0; u < 2; u++) {
        int j = Jr[u], h = Hr[u];
        float tau = Tr[u];
        int r = 0;
        for (int k = 0; k < HDIM; k++) {
            float tk = tau_u[j * HDIM + k];
            r += (tk < tau) || (tk == tau && k < h);
        }
        hs_s[j * HDIM + r] = h;
        tau_srt[j * HDIM + r] = tau;
        float mj = m_s[j];
        float P = Pr[u], kap = Kr[u];
        float sgn = (kap > 0.f) ? 1.f : ((kap < 0.f) ? -1.f : 0.f);
        pP[j * HDIM + h] = mj * sgn * P;
        pK[j * HDIM + h] = mj * sgn * kap;
        bpA[j * HDIM + h] = mj * ((kap < 0.f || (kap == 0.f && P > 0.f)) ? P : 0.f);
        bkA[j * HDIM + h] = mj * ((kap < 0.f) ? kap : 0.f);
    }
    __syncthreads();   // hs/tau_srt/coeffs ready; v_s reads done -> R2 reusable

    // ---------------- table scan for this block's 4 columns ----------------
    const int sj  = tid >> 7;           // j 0..7
    const int soc = (tid >> 5) & 3;     // oc 0..3
    const int src = tid & 31;           // chunk 0..31
    {
        float ba = 0.f, bb = 0.f, sa = 0.f, sb = 0.f;
#pragma unroll
        for (int k = 0; k < CEV; k++) {
            int h = src * CEV + k;
            float wb = W2[h * ODIM + obase + soc];
            ba = fmaf(bpA[sj * HDIM + h], wb, ba);
            bb = fmaf(bkA[sj * HDIM + h], wb, bb);
            int he = hs_s[sj * HDIM + h];          // h doubles as rank r
            float we = W2[he * ODIM + obase + soc];
            sa = fmaf(pP[sj * HDIM + he], we, sa);
            sb = fmaf(pK[sj * HDIM + he], we, sb);
        }
        cta[(sj * OC + soc) * NCHK + src] = ba;
        ctb[(sj * OC + soc) * NCHK + src] = bb;
        eta[(sj * OC + soc) * NCHK + src] = sa;
        etb[(sj * OC + soc) * NCHK + src] = sb;
    }
    __syncthreads();

    if (tid < NNODE * OC) {   // 32 owners: (j, oc)
        int j = tid >> 2, oc = tid & 3;
        float accA = 0.f, accB = 0.f;
#pragma unroll
        for (int g = 0; g < NCHK; g++) {
            accA += cta[(j * OC + oc) * NCHK + g];
            accB += ctb[(j * OC + oc) * NCHK + g];
        }
        if (j == 0) accA += b2[obase + oc];
        tabA[(j * 257) * OC + oc] = accA;
        tabB[(j * 257) * OC + oc] = accB;
#pragma unroll
        for (int g = 0; g < NCHK; g++) {
            float ta = eta[(j * OC + oc) * NCHK + g];
            float tb = etb[(j * OC + oc) * NCHK + g];
            eta[(j * OC + oc) * NCHK + g] = accA;
            etb[(j * OC + oc) * NCHK + g] = accB;
            accA += ta; accB += tb;
        }
    }
    __syncthreads();

    {
        float ra = eta[(sj * OC + soc) * NCHK + src];
        float rb = etb[(sj * OC + soc) * NCHK + src];
#pragma unroll
        for (int k = 0; k < CEV; k++) {
            int r = src * CEV + k;
            int he = hs_s[sj * HDIM + r];
            float we = W2[he * ODIM + obase + soc];
            ra = fmaf(pP[sj * HDIM + he], we, ra);
            rb = fmaf(pK[sj * HDIM + he], we, rb);
            tabA[(sj * 257 + r + 1) * OC + soc] = ra;
            tabB[(sj * 257 + r + 1) * OC + soc] = rb;
        }
    }
    __syncthreads();

    // ---------------- phase 2: 4096 samples, 4 per thread ----------------
#pragma unroll
    for (int u = 0; u < 4; u++) {
        const int s = shh * SHS + tid + u * 1024;
        const float* lp = latent + (size_t)s * FDIM;
        float4 e0 = *(const float4*)lp;
        float4 e1 = *(const float4*)(lp + 4);
        float w[NNODE] = {e0.x, e0.y, e0.z, e0.w, e1.x, e1.y, e1.z, e1.w};
        float mx = w[0];
#pragma unroll
        for (int q = 1; q < NNODE; q++) mx = fmaxf(mx, w[q]);
        float ex[NNODE];
        float sum = 0.f;
#pragma unroll
        for (int q = 0; q < NNODE; q++) { ex[q] = expf(w[q] - mx); sum += ex[q]; }
        float rinv = 1.0f / sum;

        float4 acc = {0.f, 0.f, 0.f, 0.f};
#pragma unroll
        for (int j = 0; j < NNODE; j++) {
            float c = 0.f;
#pragma unroll
            for (int q = 0; q < NNODE; q++) c = fmaf(A_s[j * 8 + q], ex[q], c);
            c *= rinv;
            int lo = 0, hi = HDIM;
            while (lo < hi) {
                int mid = (lo + hi) >> 1;
                if (tau_srt[j * HDIM + mid] < c) lo = mid + 1; else hi = mid;
            }
            float4 av = *(const float4*)&tabA[(j * 257 + lo) * OC];
            float4 bv = *(const float4*)&tabB[(j * 257 + lo) * OC];
            acc.x = fmaf(c, bv.x, acc.x + av.x);
            acc.y = fmaf(c, bv.y, acc.y + av.y);
            acc.z = fmaf(c, bv.z, acc.z + av.z);
            acc.w = fmaf(c, bv.w, acc.w + av.w);
        }
        *(float4*)&out[(size_t)s * ODIM + obase] = acc;
    }
}

extern "C" void kernel_launch(void* const* d_in, const int* in_sizes, int n_in,
                              void* d_out, int out_size, void* d_ws, size_t ws_size,
                              hipStream_t stream) {
    const float* latent = (const float*)d_in[0];
    const float* nf     = (const float*)d_in[1];
    const float* ea     = (const float*)d_in[2];
    const float* W1     = (const float*)d_in[3];
    const float* b1     = (const float*)d_in[4];
    const float* W2     = (const float*)d_in[5];
    const float* b2     = (const float*)d_in[6];
    float* out = (float*)d_out;

    hipLaunchKernelGGL(gnn_mono, dim3(NQG * NSH), dim3(1024), 0, stream,
                       latent, nf, ea, b1, W1, W2, b2, out);
}

// Round 12
// 31.888 us; speedup vs baseline: 2.5912x; 2.5912x over previous
//
#include <hip/hip_runtime.h>

#define NNODE 8
#define FDIM 512
#define HDIM 256
#define ODIM 128
#define BATCH 8192
#define SPB 32
#define NBLK (BATCH / SPB)      // 256

#define OCH 16                  // o-columns per build block
#define QCH (ODIM / OCH)        // 8
#define NGR 64                  // r-groups per build block (1024 thr)
#define CHK (HDIM / NGR)        // 4

// ws float offsets
#define OFF_TAU  0                           // tau_sorted[8][256]
#define OFF_AHAT (NNODE * HDIM)              // 2048: Ahat[64]
#define OFF_TAB  (OFF_AHAT + 128)            // 2176: float2 table [8][257][128]

// ============ K1: build, 64 blocks x 1024 threads (R10, validated) ============
__global__ __launch_bounds__(1024) void gnn_build(
    const float* __restrict__ nf, const float* __restrict__ W1,
    const float* __restrict__ ea, const float* __restrict__ b1,
    const float* __restrict__ W2, const float* __restrict__ b2,
    float* __restrict__ ws)
{
    const int tid = threadIdx.x;
    const int j = blockIdx.x >> 3;           // node 0..7
    const int q = blockIdx.x & (QCH - 1);    // o-chunk 0..7
    const int obase = q * OCH;

    __shared__ float v_s[FDIM];              // 2 KiB
    __shared__ float pp_s[4][HDIM];          // 4 KiB
    __shared__ float ss_s[4][HDIM];          // 4 KiB
    __shared__ float A_s[64], dinv_s[NNODE], m_s[NNODE];
    __shared__ float P_s[HDIM], k_s[HDIM], tau_s[HDIM];
    __shared__ int   hs_s[HDIM];
    __shared__ int   rp_s[4][HDIM];          // 4 KiB
    __shared__ float pe_s[HDIM], ke_s[HDIM], bp_s[HDIM], bk_s[HDIM];
    __shared__ float cta[NGR][OCH], ctb[NGR][OCH], eta[NGR][OCH], etb[NGR][OCH]; // 16 KiB

    // ---- A_hat in parallel ----
    if (tid < 64) {
        int i = tid >> 3, qn = tid & 7;
        float a = (i == qn) ? 1.f : 0.f;
        if (i != qn) a += ea[qn * 7 + i - (i > qn ? 1 : 0)];   // edge src=qn, dst=i
        A_s[tid] = a;
    }
    __syncthreads();
    if (tid < NNODE) {
        float d = 0.f;
#pragma unroll
        for (int qq = 0; qq < NNODE; qq++) d += A_s[tid * 8 + qq];
        dinv_s[tid] = d > 0.f ? 1.0f / sqrtf(d) : 0.f;
    }
    __syncthreads();
    if (tid < 64) {
        int i = tid >> 3, qn = tid & 7;
        A_s[tid] = dinv_s[i] * A_s[tid] * dinv_s[qn];
    }
    __syncthreads();
    if (tid < NNODE) {
        float mm = 0.f;
#pragma unroll
        for (int i = 0; i < NNODE; i++) mm += A_s[i * 8 + tid];
        m_s[tid] = mm * 0.125f;
    }
    // ---- v_j[f] (threads 0..511) ----
    if (tid < FDIM) {
        float v = 0.f;
#pragma unroll
        for (int n = 0; n < NNODE; n++) v = fmaf(A_s[j * 8 + n], nf[n * FDIM + tid], v);
        v_s[tid] = v;
    }
    __syncthreads();

    // ---- dots over f, 4-way split: h = tid&255, g = tid>>8 ----
    {
        const int h = tid & 255;
        const int g = tid >> 8;
        const float* Wp = W1 + (g * 128) * HDIM + h;
        const float* vp = v_s + g * 128;
        float pp = 0.f, ss = 0.f;
#pragma unroll 16
        for (int ff = 0; ff < 128; ff++) {
            float w = Wp[(size_t)ff * HDIM];
            pp = fmaf(vp[ff], w, pp);
            ss += w;
        }
        pp_s[g][h] = pp;
        ss_s[g][h] = ss;
    }
    __syncthreads();

    // ---- prep: P, kappa, tau, base coeffs (threads 0..255) ----
    if (tid < HDIM) {
        float P = b1[tid] + ((pp_s[0][tid] + pp_s[1][tid]) + (pp_s[2][tid] + pp_s[3][tid]));
        float s1 = ((ss_s[0][tid] + ss_s[1][tid]) + (ss_s[2][tid] + ss_s[3][tid]));
        float kap = 0.1f * s1;
        float tau = (kap != 0.f) ? (-P / kap) : __builtin_inff();
        P_s[tid] = P;
        k_s[tid] = kap;
        tau_s[tid] = tau;
        float mj = m_s[j];
        bp_s[tid] = mj * ((kap < 0.f || (kap == 0.f && P > 0.f)) ? P : 0.f);
        bk_s[tid] = mj * ((kap < 0.f) ? kap : 0.f);
    }
    __syncthreads();

    // ---- rank sort, 4-way parallel ----
    {
        const int h = tid & 255, kq = tid >> 8;
        float th = tau_s[h];
        int r = 0;
        for (int k = kq * 64; k < kq * 64 + 64; k++) {
            float tk = tau_s[k];
            r += (tk < th) || (tk == th && k < h);
        }
        rp_s[kq][h] = r;
    }
    __syncthreads();
    if (tid < HDIM) {
        int r = rp_s[0][tid] + rp_s[1][tid] + rp_s[2][tid] + rp_s[3][tid];
        hs_s[r] = tid;
        if (q == 0) ws[OFF_TAU + j * HDIM + r] = tau_s[tid];
    }
    if (blockIdx.x == 0 && tid >= 256 && tid < 320)
        ws[OFF_AHAT + tid - 256] = A_s[tid - 256];
    __syncthreads();
    if (tid < HDIM) {
        int h2 = hs_s[tid];
        float kk = k_s[h2], pp = P_s[h2];
        float sgn = (kk > 0.f) ? 1.f : ((kk < 0.f) ? -1.f : 0.f);
        float mj = m_s[j];
        pe_s[tid] = mj * sgn * pp;
        ke_s[tid] = mj * sgn * kk;
    }
    __syncthreads();

    // ---- tab pass 1: base partials + event chunk totals ----
    const int oc = tid & (OCH - 1);
    const int rr = tid >> 4;     // 0..63
    {
        float ba = 0.f, bb = 0.f, sa = 0.f, sb = 0.f;
#pragma unroll
        for (int k = 0; k < CHK; k++) {
            int h = rr * CHK + k;
            float wb = W2[h * ODIM + obase + oc];
            ba = fmaf(bp_s[h], wb, ba);
            bb = fmaf(bk_s[h], wb, bb);
            float we = W2[hs_s[h] * ODIM + obase + oc];   // h doubles as r
            sa = fmaf(pe_s[h], we, sa);
            sb = fmaf(ke_s[h], we, sb);
        }
        cta[rr][oc] = ba; ctb[rr][oc] = bb;
        eta[rr][oc] = sa; etb[rr][oc] = sb;
    }
    __syncthreads();

    float2* TAB = (float2*)(ws + OFF_TAB);

    // ---- owners: base total + row 0 + exclusive scan of 64 chunks ----
    if (tid < OCH) {
        const int o = tid;
        float accA = 0.f, accB = 0.f;
#pragma unroll
        for (int g = 0; g < NGR; g++) { accA += cta[g][o]; accB += ctb[g][o]; }
        if (j == 0) accA += b2[obase + o];
        TAB[(size_t)(j * 257) * ODIM + obase + o] = make_float2(accA, accB);
#pragma unroll
        for (int g = 0; g < NGR; g++) {
            float ta = eta[g][o], tb = etb[g][o];
            eta[g][o] = accA; etb[g][o] = accB;
            accA += ta; accB += tb;
        }
    }
    __syncthreads();

    // ---- pass 2: recompute with offset, write rows r+1 ----
    {
        float ra = eta[rr][oc], rb = etb[rr][oc];
#pragma unroll
        for (int k = 0; k < CHK; k++) {
            int r = rr * CHK + k;
            float we = W2[hs_s[r] * ODIM + obase + oc];
            ra = fmaf(pe_s[r], we, ra);
            rb = fmaf(ke_s[r], we, rb);
            TAB[(size_t)(j * 257 + r + 1) * ODIM + obase + oc] = make_float2(ra, rb);
        }
    }
}

// ============ K2: per-sample lookup + combine (256 blocks, 32 samples) ============
__global__ __launch_bounds__(256) void gnn_main(const float* __restrict__ latent,
                                                const float* __restrict__ ws,
                                                float* __restrict__ out) {
    const int t = threadIdx.x;
    const int bs = blockIdx.x * SPB;

    __shared__ float tau_s[NNODE][HDIM];   // 8 KiB
    __shared__ float A_s[64];
    __shared__ float lat_s[SPB][NNODE];    // 1 KiB
    __shared__ float cc_s[SPB][NNODE];
    __shared__ int   rr_s[SPB][NNODE];

    // tau: 2048 floats = 2 float4 per thread, coalesced
    {
        const float4* src = (const float4*)(ws + OFF_TAU);
        float4* dst = (float4*)tau_s;
        dst[t] = src[t];
        dst[t + 256] = src[t + 256];
    }
    if (t < 64) A_s[t] = ws[OFF_AHAT + t];
    // latent first 8 cols for 32 samples: 256 threads, one elem each
    {
        int s = t >> 3, qq = t & 7;
        lat_s[s][qq] = latent[(size_t)(bs + s) * FDIM + qq];
    }
    __syncthreads();

    // softmax + c + binary search: all 256 threads = 32 samples x 8 nodes
    {
        int s = t >> 3, i = t & 7;
        float mx = -1e30f;
#pragma unroll
        for (int qq = 0; qq < NNODE; qq++) mx = fmaxf(mx, lat_s[s][qq]);
        float sum = 0.f, acc = 0.f;
#pragma unroll
        for (int qq = 0; qq < NNODE; qq++) {
            float e = expf(lat_s[s][qq] - mx);
            sum += e;
            acc = fmaf(A_s[i * NNODE + qq], e, acc);
        }
        float c = acc / sum;
        cc_s[s][i] = c;
        int lo = 0, hi = HDIM;
        while (lo < hi) {
            int mid = (lo + hi) >> 1;
            if (tau_s[i][mid] < c) lo = mid + 1; else hi = mid;
        }
        rr_s[s][i] = lo;
    }
    __syncthreads();

    const int o = t & (ODIM - 1);
    const int sh = t >> 7;                 // 0 or 1
    const float2* TAB = (const float2*)(ws + OFF_TAB);

#pragma unroll 2
    for (int s = sh; s < SPB; s += 2) {
        float acc = 0.f;
#pragma unroll
        for (int jj = 0; jj < NNODE; jj++) {
            int r = rr_s[s][jj];
            float c = cc_s[s][jj];
            float2 ab = TAB[(size_t)(jj * 257 + r) * ODIM + o];
            acc += fmaf(c, ab.y, ab.x);
        }
        out[(size_t)(bs + s) * ODIM + o] = acc;
    }
}

extern "C" void kernel_launch(void* const* d_in, const int* in_sizes, int n_in,
                              void* d_out, int out_size, void* d_ws, size_t ws_size,
                              hipStream_t stream) {
    const float* latent = (const float*)d_in[0];
    const float* nf     = (const float*)d_in[1];
    const float* ea     = (const float*)d_in[2];
    const float* W1     = (const float*)d_in[3];
    const float* b1     = (const float*)d_in[4];
    const float* W2     = (const float*)d_in[5];
    const float* b2     = (const float*)d_in[6];
    float* out = (float*)d_out;
    float* ws  = (float*)d_ws;

    hipLaunchKernelGGL(gnn_build, dim3(NNODE * QCH), dim3(1024), 0, stream,
                       nf, W1, ea, b1, W2, b2, ws);
    hipLaunchKernelGGL(gnn_main, dim3(NBLK), dim3(256), 0, stream, latent, ws, out);
}

// Round 13
// 24.795 us; speedup vs baseline: 3.3324x; 1.2860x over previous
//
#include <hip/hip_runtime.h>

#define NNODE 8
#define FDIM 512
#define HDIM 256
#define ODIM 128
#define BATCH 8192
#define SPB 8
#define NBLK (BATCH / SPB)      // 1024

#define OCH 16                  // o-columns per build block
#define QCH (ODIM / OCH)        // 8
#define NGR 64                  // r-groups per build block (1024 thr)
#define CHK (HDIM / NGR)        // 4

// ws float offsets
#define OFF_TAU  0                           // tau_sorted[8][256]
#define OFF_AHAT (NNODE * HDIM)              // 2048: Ahat[64]
#define OFF_TAB  (OFF_AHAT + 128)            // 2176: float2 table [8][257][128]

// ============ K1: build, 64 blocks x 1024 threads (R10, validated) ============
__global__ __launch_bounds__(1024) void gnn_build(
    const float* __restrict__ nf, const float* __restrict__ W1,
    const float* __restrict__ ea, const float* __restrict__ b1,
    const float* __restrict__ W2, const float* __restrict__ b2,
    float* __restrict__ ws)
{
    const int tid = threadIdx.x;
    const int j = blockIdx.x >> 3;           // node 0..7
    const int q = blockIdx.x & (QCH - 1);    // o-chunk 0..7
    const int obase = q * OCH;

    __shared__ float v_s[FDIM];              // 2 KiB
    __shared__ float pp_s[4][HDIM];          // 4 KiB
    __shared__ float ss_s[4][HDIM];          // 4 KiB
    __shared__ float A_s[64], dinv_s[NNODE], m_s[NNODE];
    __shared__ float P_s[HDIM], k_s[HDIM], tau_s[HDIM];
    __shared__ int   hs_s[HDIM];
    __shared__ int   rp_s[4][HDIM];          // 4 KiB
    __shared__ float pe_s[HDIM], ke_s[HDIM], bp_s[HDIM], bk_s[HDIM];
    __shared__ float cta[NGR][OCH], ctb[NGR][OCH], eta[NGR][OCH], etb[NGR][OCH]; // 16 KiB

    // ---- A_hat in parallel ----
    if (tid < 64) {
        int i = tid >> 3, qn = tid & 7;
        float a = (i == qn) ? 1.f : 0.f;
        if (i != qn) a += ea[qn * 7 + i - (i > qn ? 1 : 0)];   // edge src=qn, dst=i
        A_s[tid] = a;
    }
    __syncthreads();
    if (tid < NNODE) {
        float d = 0.f;
#pragma unroll
        for (int qq = 0; qq < NNODE; qq++) d += A_s[tid * 8 + qq];
        dinv_s[tid] = d > 0.f ? 1.0f / sqrtf(d) : 0.f;
    }
    __syncthreads();
    if (tid < 64) {
        int i = tid >> 3, qn = tid & 7;
        A_s[tid] = dinv_s[i] * A_s[tid] * dinv_s[qn];
    }
    __syncthreads();
    if (tid < NNODE) {
        float mm = 0.f;
#pragma unroll
        for (int i = 0; i < NNODE; i++) mm += A_s[i * 8 + tid];
        m_s[tid] = mm * 0.125f;
    }
    // ---- v_j[f] (threads 0..511) ----
    if (tid < FDIM) {
        float v = 0.f;
#pragma unroll
        for (int n = 0; n < NNODE; n++) v = fmaf(A_s[j * 8 + n], nf[n * FDIM + tid], v);
        v_s[tid] = v;
    }
    __syncthreads();

    // ---- dots over f, 4-way split: h = tid&255, g = tid>>8 ----
    {
        const int h = tid & 255;
        const int g = tid >> 8;
        const float* Wp = W1 + (g * 128) * HDIM + h;
        const float* vp = v_s + g * 128;
        float pp = 0.f, ss = 0.f;
#pragma unroll 16
        for (int ff = 0; ff < 128; ff++) {
            float w = Wp[(size_t)ff * HDIM];
            pp = fmaf(vp[ff], w, pp);
            ss += w;
        }
        pp_s[g][h] = pp;
        ss_s[g][h] = ss;
    }
    __syncthreads();

    // ---- prep: P, kappa, tau, base coeffs (threads 0..255) ----
    if (tid < HDIM) {
        float P = b1[tid] + ((pp_s[0][tid] + pp_s[1][tid]) + (pp_s[2][tid] + pp_s[3][tid]));
        float s1 = ((ss_s[0][tid] + ss_s[1][tid]) + (ss_s[2][tid] + ss_s[3][tid]));
        float kap = 0.1f * s1;
        float tau = (kap != 0.f) ? (-P / kap) : __builtin_inff();
        P_s[tid] = P;
        k_s[tid] = kap;
        tau_s[tid] = tau;
        float mj = m_s[j];
        bp_s[tid] = mj * ((kap < 0.f || (kap == 0.f && P > 0.f)) ? P : 0.f);
        bk_s[tid] = mj * ((kap < 0.f) ? kap : 0.f);
    }
    __syncthreads();

    // ---- rank sort, 4-way parallel ----
    {
        const int h = tid & 255, kq = tid >> 8;
        float th = tau_s[h];
        int r = 0;
        for (int k = kq * 64; k < kq * 64 + 64; k++) {
            float tk = tau_s[k];
            r += (tk < th) || (tk == th && k < h);
        }
        rp_s[kq][h] = r;
    }
    __syncthreads();
    if (tid < HDIM) {
        int r = rp_s[0][tid] + rp_s[1][tid] + rp_s[2][tid] + rp_s[3][tid];
        hs_s[r] = tid;
        if (q == 0) ws[OFF_TAU + j * HDIM + r] = tau_s[tid];
    }
    if (blockIdx.x == 0 && tid >= 256 && tid < 320)
        ws[OFF_AHAT + tid - 256] = A_s[tid - 256];
    __syncthreads();
    if (tid < HDIM) {
        int h2 = hs_s[tid];
        float kk = k_s[h2], pp = P_s[h2];
        float sgn = (kk > 0.f) ? 1.f : ((kk < 0.f) ? -1.f : 0.f);
        float mj = m_s[j];
        pe_s[tid] = mj * sgn * pp;
        ke_s[tid] = mj * sgn * kk;
    }
    __syncthreads();

    // ---- tab pass 1: base partials + event chunk totals ----
    const int oc = tid & (OCH - 1);
    const int rr = tid >> 4;     // 0..63
    {
        float ba = 0.f, bb = 0.f, sa = 0.f, sb = 0.f;
#pragma unroll
        for (int k = 0; k < CHK; k++) {
            int h = rr * CHK + k;
            float wb = W2[h * ODIM + obase + oc];
            ba = fmaf(bp_s[h], wb, ba);
            bb = fmaf(bk_s[h], wb, bb);
            float we = W2[hs_s[h] * ODIM + obase + oc];   // h doubles as r
            sa = fmaf(pe_s[h], we, sa);
            sb = fmaf(ke_s[h], we, sb);
        }
        cta[rr][oc] = ba; ctb[rr][oc] = bb;
        eta[rr][oc] = sa; etb[rr][oc] = sb;
    }
    __syncthreads();

    float2* TAB = (float2*)(ws + OFF_TAB);

    // ---- owners: base total + row 0 + exclusive scan of 64 chunks ----
    if (tid < OCH) {
        const int o = tid;
        float accA = 0.f, accB = 0.f;
#pragma unroll
        for (int g = 0; g < NGR; g++) { accA += cta[g][o]; accB += ctb[g][o]; }
        if (j == 0) accA += b2[obase + o];
        TAB[(size_t)(j * 257) * ODIM + obase + o] = make_float2(accA, accB);
#pragma unroll
        for (int g = 0; g < NGR; g++) {
            float ta = eta[g][o], tb = etb[g][o];
            eta[g][o] = accA; etb[g][o] = accB;
            accA += ta; accB += tb;
        }
    }
    __syncthreads();

    // ---- pass 2: recompute with offset, write rows r+1 ----
    {
        float ra = eta[rr][oc], rb = etb[rr][oc];
#pragma unroll
        for (int k = 0; k < CHK; k++) {
            int r = rr * CHK + k;
            float we = W2[hs_s[r] * ODIM + obase + oc];
            ra = fmaf(pe_s[r], we, ra);
            rb = fmaf(ke_s[r], we, rb);
            TAB[(size_t)(j * 257 + r + 1) * ODIM + obase + oc] = make_float2(ra, rb);
        }
    }
}

// ============ K2: lookup, 1024 blocks x 256 thr, 8 samples each ============
__global__ __launch_bounds__(256) void gnn_main(const float* __restrict__ latent,
                                                const float* __restrict__ ws,
                                                float* __restrict__ out) {
    const int t = threadIdx.x;
    const int bs = blockIdx.x * SPB;

    __shared__ float tau_s[NNODE][HDIM];   // 8 KiB
    __shared__ float A_s[64];
    __shared__ float lat_s[SPB][NNODE];
    __shared__ float cc_s[SPB][NNODE];
    __shared__ int   rr_s[SPB][NNODE];

    // tau: 2048 floats = 512 float4, coalesced
    {
        const float4* src = (const float4*)(ws + OFF_TAU);
        float4* dst = (float4*)tau_s;
        dst[t] = src[t];
        dst[t + 256] = src[t + 256];
    }
    if (t < 64) A_s[t] = ws[OFF_AHAT + t];
    if (t >= 128 && t < 128 + SPB * NNODE) {   // 64 threads
        int u = t - 128;
        int s = u >> 3, qq = u & 7;
        lat_s[s][qq] = latent[(size_t)(bs + s) * FDIM + qq];
    }
    __syncthreads();

    if (t < SPB * NNODE) {   // 64 threads: (s, i)
        int s = t >> 3, i = t & 7;
        float mx = -1e30f;
#pragma unroll
        for (int qq = 0; qq < NNODE; qq++) mx = fmaxf(mx, lat_s[s][qq]);
        float sum = 0.f, acc = 0.f;
#pragma unroll
        for (int qq = 0; qq < NNODE; qq++) {
            float e = expf(lat_s[s][qq] - mx);
            sum += e;
            acc = fmaf(A_s[i * NNODE + qq], e, acc);
        }
        float c = acc / sum;
        cc_s[s][i] = c;
        int lo = 0, hi = HDIM;
        while (lo < hi) {
            int mid = (lo + hi) >> 1;
            if (tau_s[i][mid] < c) lo = mid + 1; else hi = mid;
        }
        rr_s[s][i] = lo;
    }
    __syncthreads();

    const int o = t & (ODIM - 1);
    const int sh = t >> 7;                 // 0 or 1
    const float2* TAB = (const float2*)(ws + OFF_TAB);

#pragma unroll
    for (int s = sh; s < SPB; s += 2) {    // 4 samples per thread
        float acc = 0.f;
#pragma unroll
        for (int jj = 0; jj < NNODE; jj++) {
            int r = rr_s[s][jj];
            float c = cc_s[s][jj];
            float2 ab = TAB[(size_t)(jj * 257 + r) * ODIM + o];
            acc += fmaf(c, ab.y, ab.x);
        }
        out[(size_t)(bs + s) * ODIM + o] = acc;
    }
}

extern "C" void kernel_launch(void* const* d_in, const int* in_sizes, int n_in,
                              void* d_out, int out_size, void* d_ws, size_t ws_size,
                              hipStream_t stream) {
    const float* latent = (const float*)d_in[0];
    const float* nf     = (const float*)d_in[1];
    const float* ea     = (const float*)d_in[2];
    const float* W1     = (const float*)d_in[3];
    const float* b1     = (const float*)d_in[4];
    const float* W2     = (const float*)d_in[5];
    const float* b2     = (const float*)d_in[6];
    float* out = (float*)d_out;
    float* ws  = (float*)d_ws;

    hipLaunchKernelGGL(gnn_build, dim3(NNODE * QCH), dim3(1024), 0, stream,
                       nf, W1, ea, b1, W2, b2, ws);
    hipLaunchKernelGGL(gnn_main, dim3(NBLK), dim3(256), 0, stream, latent, ws, out);
}